// Round 4
// baseline (235.532 us; speedup 1.0000x reference)
//
#include <hip/hip_runtime.h>

#define D 96
#define D4 24     // float4 groups per row
#define NT 64     // nodes per tile block (gemm1)
#define XPAD 97

// ===========================================================================
// CSR build: histogram of dst -> scan -> slot-fill of src ids.
// ===========================================================================
__global__ void hist_kernel(const int* __restrict__ dst, int* __restrict__ cnt, int E) {
    const int i = blockIdx.x * blockDim.x + threadIdx.x;
    if (i < E) atomicAdd(&cnt[dst[i]], 1);
}

__global__ void blockscan_kernel(const int* __restrict__ cnt, int* __restrict__ off,
                                 int* __restrict__ btot, int n) {
    __shared__ int tmp[1024];
    const int tid = threadIdx.x;
    const int gid = blockIdx.x * 1024 + tid;
    const int v = (gid < n) ? cnt[gid] : 0;
    tmp[tid] = v;
    __syncthreads();
    for (int ofs = 1; ofs < 1024; ofs <<= 1) {
        int t = 0;
        if (tid >= ofs) t = tmp[tid - ofs];
        __syncthreads();
        if (tid >= ofs) tmp[tid] += t;
        __syncthreads();
    }
    if (gid < n) off[gid] = tmp[tid] - v;
    if (tid == 1023) btot[blockIdx.x] = tmp[1023];
}

__global__ void scantot_kernel(int* __restrict__ btot, int nb) {
    const int tid = threadIdx.x;
    if (nb <= 64) {
        if (tid < 64) {
            const int v0 = (tid < nb) ? btot[tid] : 0;
            int v = v0;
            for (int ofs = 1; ofs < 64; ofs <<= 1) {
                const int t = __shfl_up(v, ofs, 64);
                if (tid >= ofs) v += t;
            }
            if (tid < nb) btot[tid] = v - v0;
        }
    } else if (tid == 0) {
        int run = 0;
        for (int i = 0; i < nb; ++i) { const int v = btot[i]; btot[i] = run; run += v; }
    }
}

__global__ void addoff_kernel(int* __restrict__ off, int* __restrict__ cursor,
                              const int* __restrict__ btot, int n) {
    const int i = blockIdx.x * blockDim.x + threadIdx.x;
    if (i < n) {
        const int o = off[i] + btot[i >> 10];
        off[i] = o;
        cursor[i] = o;
    }
}

__global__ void fill_kernel(const int* __restrict__ src, const int* __restrict__ dst,
                            int* __restrict__ cursor, int* __restrict__ srcs, int E) {
    const int i = blockIdx.x * blockDim.x + threadIdx.x;
    if (i < E) {
        const int p = atomicAdd(&cursor[dst[i]], 1);
        srcs[p] = src[i];
    }
}

// ===========================================================================
// gemm1: y = x @ W1  (no bias; b1 folded into gather1).
// Block = 64 nodes x 4 quarters. x tile + W1 staged in LDS.
// ===========================================================================
__global__ __launch_bounds__(256, 2)
void gemm1_kernel(const float* __restrict__ x,
                  const float* __restrict__ W,   // [96][96] [k][o]
                  float* __restrict__ y, int n) {
    __shared__ float Xs[NT][XPAD];     // 24.8 KB
    __shared__ float4 Ws[D * D4];      // 36.9 KB

    const int tid = threadIdx.x;
    for (int i = tid; i < D * D4; i += 256)
        Ws[i] = ((const float4*)W)[i];

    const int node_l = tid >> 2;
    const int qq = tid & 3;
    const int node = blockIdx.x * NT + node_l;

    if (node < n) {
        const float4* xr = ((const float4*)(x + (size_t)node * D)) + qq * 6;
#pragma unroll
        for (int j = 0; j < 6; ++j) {
            const float4 v = xr[j];
            Xs[node_l][qq * 24 + j * 4 + 0] = v.x;
            Xs[node_l][qq * 24 + j * 4 + 1] = v.y;
            Xs[node_l][qq * 24 + j * 4 + 2] = v.z;
            Xs[node_l][qq * 24 + j * 4 + 3] = v.w;
        }
    }
    __syncthreads();

    if (node < n) {
        float4 oacc[6];
#pragma unroll
        for (int j = 0; j < 6; ++j) oacc[j] = make_float4(0.f, 0.f, 0.f, 0.f);
#pragma unroll 4
        for (int k = 0; k < D; ++k) {
            const float xv = Xs[node_l][k];
            const float4* wrow = Ws + k * D4 + qq * 6;
#pragma unroll
            for (int j = 0; j < 6; ++j) {
                const float4 w = wrow[j];
                oacc[j].x += xv * w.x; oacc[j].y += xv * w.y;
                oacc[j].z += xv * w.z; oacc[j].w += xv * w.w;
            }
        }
        float4* yr = ((float4*)(y + (size_t)node * D)) + qq * 6;
#pragma unroll
        for (int j = 0; j < 6; ++j) yr[j] = oacc[j];
    }
}

// ===========================================================================
// gather1: h = relu(y[node] + sum_src y[src] + b1).
// Thread = (node, quarter). No LDS -> high occupancy. 2-edge ILP.
// ===========================================================================
__global__ __launch_bounds__(256)
void gather1_kernel(const float* __restrict__ y,
                    const float* __restrict__ b,   // [96]
                    const int* __restrict__ off,
                    const int* __restrict__ cnt,
                    const int* __restrict__ srcs,
                    float* __restrict__ h, int n) {
    const int t = blockIdx.x * blockDim.x + threadIdx.x;
    const int node = t >> 2;
    const int qq = t & 3;
    if (node >= n) return;

    float4 acc[6];
    {
        const float4* yr = ((const float4*)(y + (size_t)node * D)) + qq * 6;
#pragma unroll
        for (int j = 0; j < 6; ++j) acc[j] = yr[j];
    }

    const int s0 = off[node];
    const int deg = cnt[node];
    int p = 0;
    for (; p + 2 <= deg; p += 2) {
        const int sA = srcs[s0 + p];
        const int sB = srcs[s0 + p + 1];
        const float4* rA = ((const float4*)(y + (size_t)sA * D)) + qq * 6;
        const float4* rB = ((const float4*)(y + (size_t)sB * D)) + qq * 6;
#pragma unroll
        for (int j = 0; j < 6; ++j) {
            const float4 a = rA[j];
            const float4 c = rB[j];
            acc[j].x += a.x + c.x; acc[j].y += a.y + c.y;
            acc[j].z += a.z + c.z; acc[j].w += a.w + c.w;
        }
    }
    if (p < deg) {
        const int sA = srcs[s0 + p];
        const float4* rA = ((const float4*)(y + (size_t)sA * D)) + qq * 6;
#pragma unroll
        for (int j = 0; j < 6; ++j) {
            const float4 a = rA[j];
            acc[j].x += a.x; acc[j].y += a.y;
            acc[j].z += a.z; acc[j].w += a.w;
        }
    }

    const float4* bb = ((const float4*)b) + qq * 6;
    float4* hr = ((float4*)(h + (size_t)node * D)) + qq * 6;
#pragma unroll
    for (int j = 0; j < 6; ++j) {
        const float4 bv = bb[j];
        float4 v = acc[j];
        v.x = fmaxf(v.x + bv.x, 0.0f);
        v.y = fmaxf(v.y + bv.y, 0.0f);
        v.z = fmaxf(v.z + bv.z, 0.0f);
        v.w = fmaxf(v.w + bv.w, 0.0f);
        hr[j] = v;
    }
}

// ===========================================================================
// gemm2: z = h @ W2   (z is [n][2]; b2 folded into gather2).
// ===========================================================================
__global__ __launch_bounds__(256)
void gemm2_kernel(const float* __restrict__ h,
                  const float* __restrict__ W,   // [96][2]
                  float* __restrict__ z, int n) {
    __shared__ float W2s[D * 2];
    const int tid = threadIdx.x;
    if (tid < D * 2) W2s[tid] = W[tid];
    __syncthreads();

    const int node = blockIdx.x * blockDim.x + tid;
    if (node >= n) return;

    float a0 = 0.f, a1 = 0.f;
    const float4* hr = (const float4*)(h + (size_t)node * D);
#pragma unroll
    for (int q = 0; q < D4; ++q) {
        const float4 v = hr[q];
        const int k = q * 4;
        a0 += v.x * W2s[2 * k + 0] + v.y * W2s[2 * k + 2] +
              v.z * W2s[2 * k + 4] + v.w * W2s[2 * k + 6];
        a1 += v.x * W2s[2 * k + 1] + v.y * W2s[2 * k + 3] +
              v.z * W2s[2 * k + 5] + v.w * W2s[2 * k + 7];
    }
    ((float2*)z)[node] = make_float2(a0, a1);
}

// ===========================================================================
// gather2: out = z[node] + sum_src z[src] + b2.  z is tiny (400 KB, L2-hot).
// ===========================================================================
__global__ __launch_bounds__(256)
void gather2_kernel(const float* __restrict__ z,
                    const float* __restrict__ b,   // [2]
                    const int* __restrict__ off,
                    const int* __restrict__ cnt,
                    const int* __restrict__ srcs,
                    float* __restrict__ out, int n) {
    const int node = blockIdx.x * blockDim.x + threadIdx.x;
    if (node >= n) return;

    const float2 zi = ((const float2*)z)[node];
    float a0 = zi.x + b[0];
    float a1 = zi.y + b[1];

    const int s0 = off[node];
    const int deg = cnt[node];
    int p = 0;
    for (; p + 2 <= deg; p += 2) {
        const float2 vA = ((const float2*)z)[srcs[s0 + p]];
        const float2 vB = ((const float2*)z)[srcs[s0 + p + 1]];
        a0 += vA.x + vB.x;
        a1 += vA.y + vB.y;
    }
    if (p < deg) {
        const float2 vA = ((const float2*)z)[srcs[s0 + p]];
        a0 += vA.x;
        a1 += vA.y;
    }
    ((float2*)out)[node] = make_float2(a0, a1);
}

// ===========================================================================
// Fallback (atomic scatter) path — used only if ws too small.
// ===========================================================================
__global__ void scatter_add_kernel(const float* __restrict__ x,
                                   const int* __restrict__ src,
                                   const int* __restrict__ dst,
                                   float* __restrict__ aggr, int E) {
    const int total = E * D4;
    for (int i = blockIdx.x * blockDim.x + threadIdx.x; i < total;
         i += gridDim.x * blockDim.x) {
        const int e = i / D4;
        const int q = i - e * D4;
        const float4 v = ((const float4*)(x + (size_t)src[e] * D))[q];
        float* a = aggr + (size_t)dst[e] * D + q * 4;
        atomicAdd(a + 0, v.x);
        atomicAdd(a + 1, v.y);
        atomicAdd(a + 2, v.z);
        atomicAdd(a + 3, v.w);
    }
}

__global__ void lin1_relu_fb_kernel(const float* __restrict__ x,
                                    const float* __restrict__ aggr,
                                    const float* __restrict__ W,
                                    const float* __restrict__ b,
                                    float* __restrict__ h, int n) {
    const int t = blockIdx.x * blockDim.x + threadIdx.x;
    const int node = t >> 2, qq = t & 3;
    if (node >= n) return;
    float4 oacc[6];
#pragma unroll
    for (int j = 0; j < 6; ++j) oacc[j] = ((const float4*)b)[qq * 6 + j];
    for (int k = 0; k < D; ++k) {
        const float xv = x[(size_t)node * D + k] + aggr[(size_t)node * D + k];
#pragma unroll
        for (int j = 0; j < 6; ++j) {
            const float4 w = ((const float4*)W)[k * D4 + qq * 6 + j];
            oacc[j].x += xv * w.x; oacc[j].y += xv * w.y;
            oacc[j].z += xv * w.z; oacc[j].w += xv * w.w;
        }
    }
    float4* hr = ((float4*)(h + (size_t)node * D)) + qq * 6;
#pragma unroll
    for (int j = 0; j < 6; ++j) {
        float4 v = oacc[j];
        v.x = fmaxf(v.x, 0.0f); v.y = fmaxf(v.y, 0.0f);
        v.z = fmaxf(v.z, 0.0f); v.w = fmaxf(v.w, 0.0f);
        hr[j] = v;
    }
}

__global__ void lin2_fb_kernel(const float* __restrict__ h,
                               const float* __restrict__ aggr,
                               const float* __restrict__ W,
                               const float* __restrict__ b,
                               float* __restrict__ out, int n) {
    const int node = blockIdx.x * blockDim.x + threadIdx.x;
    if (node >= n) return;
    float a0 = b[0], a1 = b[1];
    for (int k = 0; k < D; ++k) {
        const float v = h[(size_t)node * D + k] + aggr[(size_t)node * D + k];
        a0 += v * W[2 * k + 0];
        a1 += v * W[2 * k + 1];
    }
    out[(size_t)node * 2 + 0] = a0;
    out[(size_t)node * 2 + 1] = a1;
}

// ===========================================================================
extern "C" void kernel_launch(void* const* d_in, const int* in_sizes, int n_in,
                              void* d_out, int out_size, void* d_ws, size_t ws_size,
                              hipStream_t stream) {
    const float* x   = (const float*)d_in[0];
    const int*   eix = (const int*)d_in[1];
    const float* W1  = (const float*)d_in[2];
    const float* b1  = (const float*)d_in[3];
    const float* W2  = (const float*)d_in[4];
    const float* b2  = (const float*)d_in[5];
    float*       out = (float*)d_out;

    const int n = in_sizes[0] / D;       // 50000
    const int E = in_sizes[1] / 2;       // 800000
    const int* src = eix;
    const int* dst = eix + E;

    const size_t rowf = (size_t)n * D;
    const int nb = (n + 1023) / 1024;

    // ws layout: y | h | cnt | off | cursor | btot(1024) | srcs
    // (z reuses the y buffer after gather1 has consumed y)
    const size_t need = 2 * rowf * sizeof(float) +
                        (size_t)(3 * n + 1024 + E) * sizeof(int);

    float* y = (float*)d_ws;
    float* h = y + rowf;

    if (ws_size < need) {
        float* aggr = h;   // reuse naming: y=scratch0, h=scratch1
        hipMemsetAsync(y, 0, rowf * sizeof(float), stream);
        scatter_add_kernel<<<4096, 256, 0, stream>>>(x, src, dst, y, E);
        lin1_relu_fb_kernel<<<(4 * n + 255) / 256, 256, 0, stream>>>(x, y, W1, b1, aggr, n);
        hipMemsetAsync(y, 0, rowf * sizeof(float), stream);
        scatter_add_kernel<<<4096, 256, 0, stream>>>(aggr, src, dst, y, E);
        lin2_fb_kernel<<<(n + 255) / 256, 256, 0, stream>>>(aggr, y, W2, b2, out, n);
        return;
    }

    int* cnt    = (int*)(h + rowf);
    int* off    = cnt + n;
    int* cursor = off + n;
    int* btot   = cursor + n;
    int* srcs   = btot + 1024;

    // ---- CSR build (once; reused by both layers) ----
    hipMemsetAsync(cnt, 0, (size_t)n * sizeof(int), stream);
    hist_kernel<<<(E + 255) / 256, 256, 0, stream>>>(dst, cnt, E);
    blockscan_kernel<<<nb, 1024, 0, stream>>>(cnt, off, btot, n);
    scantot_kernel<<<1, 64, 0, stream>>>(btot, nb);
    addoff_kernel<<<(n + 255) / 256, 256, 0, stream>>>(off, cursor, btot, n);
    fill_kernel<<<(E + 255) / 256, 256, 0, stream>>>(src, dst, cursor, srcs, E);

    const int tiles = (n + NT - 1) / NT;          // 782
    const int qthreads_blocks = (4 * n + 255) / 256;
    const int nthreads_blocks = (n + 255) / 256;

    // ---- Layer 1: y = x@W1, then h = relu(y_i + sum y_src + b1) ----
    gemm1_kernel<<<tiles, 256, 0, stream>>>(x, W1, y, n);
    gather1_kernel<<<qthreads_blocks, 256, 0, stream>>>(y, b1, off, cnt, srcs, h, n);

    // ---- Layer 2: z = h@W2 (reuse y buffer), out = z_i + sum z_src + b2 ----
    float* z = y;
    gemm2_kernel<<<nthreads_blocks, 256, 0, stream>>>(h, W2, z, n);
    gather2_kernel<<<nthreads_blocks, 256, 0, stream>>>(z, b2, off, cnt, srcs, out, n);
}

// Round 5
// 184.310 us; speedup vs baseline: 1.2779x; 1.2779x over previous
//
#include <hip/hip_runtime.h>

#define D 96
#define D4 24     // float4 groups per row
#define NT 64     // nodes per tile block (gemm1)
#define XPAD 97

typedef unsigned int uint32;
typedef unsigned short ushort16;

// Round-to-nearest-even f32 -> bf16, packed pair (a in low 16, b in high 16).
__device__ __forceinline__ uint32 pk_bf16(float a, float b) {
    uint32 ua = __float_as_uint(a);
    uint32 ub = __float_as_uint(b);
    ua = (ua + 0x7fffu + ((ua >> 16) & 1u)) >> 16;
    ub = (ub + 0x7fffu + ((ub >> 16) & 1u)) & 0xffff0000u;
    return (ua & 0xffffu) | ub;
}

// unpack a uint4 (8 bf16) and add into acc[o..o+7]; _SET variant initializes.
#define UNPK_ADD(u, o) \
    acc[(o)+0] += __uint_as_float((u).x << 16); \
    acc[(o)+1] += __uint_as_float((u).x & 0xffff0000u); \
    acc[(o)+2] += __uint_as_float((u).y << 16); \
    acc[(o)+3] += __uint_as_float((u).y & 0xffff0000u); \
    acc[(o)+4] += __uint_as_float((u).z << 16); \
    acc[(o)+5] += __uint_as_float((u).z & 0xffff0000u); \
    acc[(o)+6] += __uint_as_float((u).w << 16); \
    acc[(o)+7] += __uint_as_float((u).w & 0xffff0000u);

#define UNPK_SET(u, o) \
    acc[(o)+0] = __uint_as_float((u).x << 16); \
    acc[(o)+1] = __uint_as_float((u).x & 0xffff0000u); \
    acc[(o)+2] = __uint_as_float((u).y << 16); \
    acc[(o)+3] = __uint_as_float((u).y & 0xffff0000u); \
    acc[(o)+4] = __uint_as_float((u).z << 16); \
    acc[(o)+5] = __uint_as_float((u).z & 0xffff0000u); \
    acc[(o)+6] = __uint_as_float((u).w << 16); \
    acc[(o)+7] = __uint_as_float((u).w & 0xffff0000u);

// ===========================================================================
// init: zero cnt and z (replaces two memsets).
// ===========================================================================
__global__ void init_kernel(int* __restrict__ cnt, float2* __restrict__ z, int n) {
    const int i = blockIdx.x * blockDim.x + threadIdx.x;
    if (i < n) {
        cnt[i] = 0;
        z[i] = make_float2(0.f, 0.f);
    }
}

// ===========================================================================
// CSR build: histogram of dst -> scan -> slot-fill of src ids.
// ===========================================================================
__global__ void hist_kernel(const int* __restrict__ dst, int* __restrict__ cnt, int E) {
    const int i = blockIdx.x * blockDim.x + threadIdx.x;
    if (i < E) atomicAdd(&cnt[dst[i]], 1);
}

__global__ void blockscan_kernel(const int* __restrict__ cnt, int* __restrict__ off,
                                 int* __restrict__ btot, int n) {
    __shared__ int tmp[1024];
    const int tid = threadIdx.x;
    const int gid = blockIdx.x * 1024 + tid;
    const int v = (gid < n) ? cnt[gid] : 0;
    tmp[tid] = v;
    __syncthreads();
    for (int ofs = 1; ofs < 1024; ofs <<= 1) {
        int t = 0;
        if (tid >= ofs) t = tmp[tid - ofs];
        __syncthreads();
        if (tid >= ofs) tmp[tid] += t;
        __syncthreads();
    }
    if (gid < n) off[gid] = tmp[tid] - v;
    if (tid == 1023) btot[blockIdx.x] = tmp[1023];
}

__global__ void scantot_kernel(int* __restrict__ btot, int nb) {
    const int tid = threadIdx.x;
    if (nb <= 64) {
        if (tid < 64) {
            const int v0 = (tid < nb) ? btot[tid] : 0;
            int v = v0;
            for (int ofs = 1; ofs < 64; ofs <<= 1) {
                const int t = __shfl_up(v, ofs, 64);
                if (tid >= ofs) v += t;
            }
            if (tid < nb) btot[tid] = v - v0;
        }
    } else if (tid == 0) {
        int run = 0;
        for (int i = 0; i < nb; ++i) { const int v = btot[i]; btot[i] = run; run += v; }
    }
}

__global__ void addoff_kernel(int* __restrict__ off, int* __restrict__ cursor,
                              const int* __restrict__ btot, int n) {
    const int i = blockIdx.x * blockDim.x + threadIdx.x;
    if (i < n) {
        const int o = off[i] + btot[i >> 10];
        off[i] = o;
        cursor[i] = o;
    }
}

__global__ void fill_kernel(const int* __restrict__ src, const int* __restrict__ dst,
                            int* __restrict__ cursor, int* __restrict__ srcs, int E) {
    const int i = blockIdx.x * blockDim.x + threadIdx.x;
    if (i < E) {
        const int p = atomicAdd(&cursor[dst[i]], 1);
        srcs[p] = src[i];
    }
}

// ===========================================================================
// gemm1: y = x @ W1, output bf16 in QUARTER-MAJOR layout:
//   yq[((q*n)+node)*24 + j] = bf16( (x@W1)[node][q*24+j] )
// Each quarter slab is n*48 B = 2.4 MB -> fits one XCD's 4 MB L2.
// ===========================================================================
__global__ __launch_bounds__(256, 2)
void gemm1_kernel(const float* __restrict__ x,
                  const float* __restrict__ W,   // [96][96] [k][o]
                  ushort16* __restrict__ yq, int n) {
    __shared__ float Xs[NT][XPAD];     // 24.8 KB
    __shared__ float4 Ws[D * D4];      // 36.9 KB

    const int tid = threadIdx.x;
    for (int i = tid; i < D * D4; i += 256)
        Ws[i] = ((const float4*)W)[i];

    const int node_l = tid >> 2;
    const int qq = tid & 3;            // output-column quarter
    const int node = blockIdx.x * NT + node_l;

    if (node < n) {
        const float4* xr = ((const float4*)(x + (size_t)node * D)) + qq * 6;
#pragma unroll
        for (int j = 0; j < 6; ++j) {
            const float4 v = xr[j];
            Xs[node_l][qq * 24 + j * 4 + 0] = v.x;
            Xs[node_l][qq * 24 + j * 4 + 1] = v.y;
            Xs[node_l][qq * 24 + j * 4 + 2] = v.z;
            Xs[node_l][qq * 24 + j * 4 + 3] = v.w;
        }
    }
    __syncthreads();

    if (node < n) {
        float4 oacc[6];
#pragma unroll
        for (int j = 0; j < 6; ++j) oacc[j] = make_float4(0.f, 0.f, 0.f, 0.f);
#pragma unroll 4
        for (int k = 0; k < D; ++k) {
            const float xv = Xs[node_l][k];
            const float4* wrow = Ws + k * D4 + qq * 6;
#pragma unroll
            for (int j = 0; j < 6; ++j) {
                const float4 w = wrow[j];
                oacc[j].x += xv * w.x; oacc[j].y += xv * w.y;
                oacc[j].z += xv * w.z; oacc[j].w += xv * w.w;
            }
        }
        // pack 24 f32 -> 12 dwords bf16, store 48 B to quarter-major slab
        uint32 p[12];
#pragma unroll
        for (int j = 0; j < 6; ++j) {
            p[2 * j + 0] = pk_bf16(oacc[j].x, oacc[j].y);
            p[2 * j + 1] = pk_bf16(oacc[j].z, oacc[j].w);
        }
        uint4* dst = (uint4*)(yq + ((size_t)qq * n + node) * 24);
        dst[0] = make_uint4(p[0], p[1], p[2], p[3]);
        dst[1] = make_uint4(p[4], p[5], p[6], p[7]);
        dst[2] = make_uint4(p[8], p[9], p[10], p[11]);
    }
}

// ===========================================================================
// gather1z: per (node, quarter):
//   hq = relu( yq[node] + sum_src yq[src] + b1_q )     (24 values, registers)
//   (z0,z1) = hq . W2_q ; atomicAdd into z[node]
// Quarter is bound to an XCD pair via blockIdx (%8 round-robin) so each
// XCD's L2 only sees one 2.4 MB slab.
// ===========================================================================
__global__ __launch_bounds__(256)
void gather1z_kernel(const ushort16* __restrict__ yq,
                     const float* __restrict__ b1,   // [96]
                     const float* __restrict__ W2,   // [96][2]
                     const int* __restrict__ off,
                     const int* __restrict__ cnt,
                     const int* __restrict__ srcs,
                     float* __restrict__ z,          // [n][2], pre-zeroed
                     int n, int bpq) {
    const int blk = blockIdx.x;
    const int q = (blk & 7) >> 1;                    // XCDs {2q, 2q+1} -> quarter q
    const int i = ((blk >> 3) << 1) | (blk & 1);     // node-block within quarter
    if (i >= bpq) return;
    const int node = i * 256 + threadIdx.x;
    if (node >= n) return;

    const uint4* Y = (const uint4*)(yq + (size_t)q * n * 24);  // 3 uint4 per row

    float acc[24];
    {
        const uint4* r = Y + (size_t)node * 3;
        const uint4 u0 = r[0], u1 = r[1], u2 = r[2];
        UNPK_SET(u0, 0) UNPK_SET(u1, 8) UNPK_SET(u2, 16)
    }

    const int s0 = off[node];
    const int deg = cnt[node];
    int p = 0;
    for (; p + 2 <= deg; p += 2) {
        const int sA = srcs[s0 + p];
        const int sB = srcs[s0 + p + 1];
        const uint4* rA = Y + (size_t)sA * 3;
        const uint4* rB = Y + (size_t)sB * 3;
        const uint4 a0 = rA[0], a1 = rA[1], a2 = rA[2];
        const uint4 c0 = rB[0], c1 = rB[1], c2 = rB[2];
        UNPK_ADD(a0, 0) UNPK_ADD(a1, 8) UNPK_ADD(a2, 16)
        UNPK_ADD(c0, 0) UNPK_ADD(c1, 8) UNPK_ADD(c2, 16)
    }
    if (p < deg) {
        const uint4* rA = Y + (size_t)srcs[s0 + p] * 3;
        const uint4 a0 = rA[0], a1 = rA[1], a2 = rA[2];
        UNPK_ADD(a0, 0) UNPK_ADD(a1, 8) UNPK_ADD(a2, 16)
    }

    // epilogue: bias + relu + dot with W2 quarter slice, accumulate into z
    const float* bq = b1 + q * 24;
    const float* wq = W2 + q * 48;     // 24 rows x 2 cols
    float z0 = 0.f, z1 = 0.f;
#pragma unroll
    for (int j = 0; j < 24; ++j) {
        const float hv = fmaxf(acc[j] + bq[j], 0.0f);
        z0 += hv * wq[2 * j + 0];
        z1 += hv * wq[2 * j + 1];
    }
    atomicAdd(&z[2 * node + 0], z0);
    atomicAdd(&z[2 * node + 1], z1);
}

// ===========================================================================
// gather2: out = z[node] + sum_src z[src] + b2.  z is 400 KB, L2-hot.
// ===========================================================================
__global__ __launch_bounds__(256)
void gather2_kernel(const float* __restrict__ z,
                    const float* __restrict__ b,   // [2]
                    const int* __restrict__ off,
                    const int* __restrict__ cnt,
                    const int* __restrict__ srcs,
                    float* __restrict__ out, int n) {
    const int node = blockIdx.x * blockDim.x + threadIdx.x;
    if (node >= n) return;

    const float2 zi = ((const float2*)z)[node];
    float a0 = zi.x + b[0];
    float a1 = zi.y + b[1];

    const int s0 = off[node];
    const int deg = cnt[node];
    int p = 0;
    for (; p + 2 <= deg; p += 2) {
        const float2 vA = ((const float2*)z)[srcs[s0 + p]];
        const float2 vB = ((const float2*)z)[srcs[s0 + p + 1]];
        a0 += vA.x + vB.x;
        a1 += vA.y + vB.y;
    }
    if (p < deg) {
        const float2 vA = ((const float2*)z)[srcs[s0 + p]];
        a0 += vA.x;
        a1 += vA.y;
    }
    ((float2*)out)[node] = make_float2(a0, a1);
}

// ===========================================================================
extern "C" void kernel_launch(void* const* d_in, const int* in_sizes, int n_in,
                              void* d_out, int out_size, void* d_ws, size_t ws_size,
                              hipStream_t stream) {
    const float* x   = (const float*)d_in[0];
    const int*   eix = (const int*)d_in[1];
    const float* W1  = (const float*)d_in[2];
    const float* b1  = (const float*)d_in[3];
    const float* W2  = (const float*)d_in[4];
    const float* b2  = (const float*)d_in[5];
    float*       out = (float*)d_out;

    const int n = in_sizes[0] / D;       // 50000
    const int E = in_sizes[1] / 2;       // 800000
    const int* src = eix;
    const int* dst = eix + E;

    const int nb = (n + 1023) / 1024;

    // ws layout: yq (bf16, n*96) | z (f32, n*2) | cnt | off | cursor | btot | srcs
    ushort16* yq = (ushort16*)d_ws;
    float* z     = (float*)(yq + (size_t)n * D);
    int* cnt     = (int*)(z + 2 * (size_t)n);
    int* off     = cnt + n;
    int* cursor  = off + n;
    int* btot    = cursor + n;
    int* srcs    = btot + 1024;

    // ---- init + CSR build (reused by both layers) ----
    init_kernel<<<(n + 255) / 256, 256, 0, stream>>>(cnt, (float2*)z, n);
    hist_kernel<<<(E + 255) / 256, 256, 0, stream>>>(dst, cnt, E);
    blockscan_kernel<<<nb, 1024, 0, stream>>>(cnt, off, btot, n);
    scantot_kernel<<<1, 64, 0, stream>>>(btot, nb);
    addoff_kernel<<<(n + 255) / 256, 256, 0, stream>>>(off, cursor, btot, n);
    fill_kernel<<<(E + 255) / 256, 256, 0, stream>>>(src, dst, cursor, srcs, E);

    // ---- layer 1 GEMM: y = x@W1 (bf16, quarter-major) ----
    const int tiles = (n + NT - 1) / NT;
    gemm1_kernel<<<tiles, 256, 0, stream>>>(x, W1, yq, n);

    // ---- fused gather + bias/relu + W2 projection -> z ----
    const int bpq = (n + 255) / 256;                 // node-blocks per quarter
    const int g1grid = 8 * ((bpq + 1) / 2);
    gather1z_kernel<<<g1grid, 256, 0, stream>>>(yq, b1, W2, off, cnt, srcs, z, n, bpq);

    // ---- layer 2 gather: out = z_i + sum z_src + b2 ----
    gather2_kernel<<<(n + 255) / 256, 256, 0, stream>>>(z, b2, off, cnt, srcs, out, n);
}

// Round 6
// 169.582 us; speedup vs baseline: 1.3889x; 1.0868x over previous
//
#include <hip/hip_runtime.h>

#define D 96
#define D4 24     // float4 groups per row
#define NT 64     // nodes per tile block (gemm1)
#define XPAD 97
#define NXCD 8

typedef unsigned int uint32;
typedef unsigned short ushort16;

// Round-to-nearest-even f32 -> bf16, packed pair (a in low 16, b in high 16).
__device__ __forceinline__ uint32 pk_bf16(float a, float b) {
    uint32 ua = __float_as_uint(a);
    uint32 ub = __float_as_uint(b);
    ua = (ua + 0x7fffu + ((ua >> 16) & 1u)) >> 16;
    ub = (ub + 0x7fffu + ((ub >> 16) & 1u)) & 0xffff0000u;
    return (ua & 0xffffu) | ub;
}

#define UNPK_ADD(u, o) \
    acc[(o)+0] += __uint_as_float((u).x << 16); \
    acc[(o)+1] += __uint_as_float((u).x & 0xffff0000u); \
    acc[(o)+2] += __uint_as_float((u).y << 16); \
    acc[(o)+3] += __uint_as_float((u).y & 0xffff0000u); \
    acc[(o)+4] += __uint_as_float((u).z << 16); \
    acc[(o)+5] += __uint_as_float((u).z & 0xffff0000u); \
    acc[(o)+6] += __uint_as_float((u).w << 16); \
    acc[(o)+7] += __uint_as_float((u).w & 0xffff0000u);

#define UNPK_SET(u, o) \
    acc[(o)+0] = __uint_as_float((u).x << 16); \
    acc[(o)+1] = __uint_as_float((u).x & 0xffff0000u); \
    acc[(o)+2] = __uint_as_float((u).y << 16); \
    acc[(o)+3] = __uint_as_float((u).y & 0xffff0000u); \
    acc[(o)+4] = __uint_as_float((u).z << 16); \
    acc[(o)+5] = __uint_as_float((u).z & 0xffff0000u); \
    acc[(o)+6] = __uint_as_float((u).w << 16); \
    acc[(o)+7] = __uint_as_float((u).w & 0xffff0000u);

// ===========================================================================
// init: zero cnt and z (replaces memsets).
// ===========================================================================
__global__ void init_kernel(int* __restrict__ cnt, float2* __restrict__ z, int n) {
    const int i = blockIdx.x * blockDim.x + threadIdx.x;
    if (i < n) {
        cnt[i] = 0;
        z[i] = make_float2(0.f, 0.f);
    }
}

// ===========================================================================
// XCD-partitioned histogram: block handles only dst in its XCD's node range.
// Each edge is read by 8 blocks but processed by exactly 1 (range filter),
// so cnt atomics stay in one XCD's L2 (~25 KB range).
// ===========================================================================
__global__ __launch_bounds__(256)
void hist_x_kernel(const int* __restrict__ dst, int* __restrict__ cnt,
                   int E, int nper, int nGroups) {
    const int xcd = blockIdx.x & (NXCD - 1);
    const int g = blockIdx.x >> 3;
    const int lo = xcd * nper, hi = lo + nper;
    for (int i = g * 256 + (int)threadIdx.x; i < E; i += nGroups * 256) {
        const int d = dst[i];
        if (d >= lo && d < hi) atomicAdd(&cnt[d], 1);
    }
}

// ===========================================================================
// XCD-partitioned slot-fill: same filter; srcs writes land in a contiguous
// ~E/8 slot range per XCD (CSR offsets monotone in dst) -> L2-local, lines
// fully written before eviction (fixes 52 MB -> ~6 MB write amplification).
// ===========================================================================
__global__ __launch_bounds__(256)
void fill_x_kernel(const int* __restrict__ src, const int* __restrict__ dst,
                   int* __restrict__ cursor, int* __restrict__ srcs,
                   int E, int nper, int nGroups) {
    const int xcd = blockIdx.x & (NXCD - 1);
    const int g = blockIdx.x >> 3;
    const int lo = xcd * nper, hi = lo + nper;
    for (int i = g * 256 + (int)threadIdx.x; i < E; i += nGroups * 256) {
        const int d = dst[i];
        if (d >= lo && d < hi) {
            const int p = atomicAdd(&cursor[d], 1);
            srcs[p] = src[i];
        }
    }
}

// ===========================================================================
// Scan: per-block inclusive scan -> block totals -> wave scan -> add-off.
// ===========================================================================
__global__ void blockscan_kernel(const int* __restrict__ cnt, int* __restrict__ off,
                                 int* __restrict__ btot, int n) {
    __shared__ int tmp[1024];
    const int tid = threadIdx.x;
    const int gid = blockIdx.x * 1024 + tid;
    const int v = (gid < n) ? cnt[gid] : 0;
    tmp[tid] = v;
    __syncthreads();
    for (int ofs = 1; ofs < 1024; ofs <<= 1) {
        int t = 0;
        if (tid >= ofs) t = tmp[tid - ofs];
        __syncthreads();
        if (tid >= ofs) tmp[tid] += t;
        __syncthreads();
    }
    if (gid < n) off[gid] = tmp[tid] - v;
    if (tid == 1023) btot[blockIdx.x] = tmp[1023];
}

__global__ void scantot_kernel(int* __restrict__ btot, int nb) {
    const int tid = threadIdx.x;
    if (nb <= 64) {
        if (tid < 64) {
            const int v0 = (tid < nb) ? btot[tid] : 0;
            int v = v0;
            for (int ofs = 1; ofs < 64; ofs <<= 1) {
                const int t = __shfl_up(v, ofs, 64);
                if (tid >= ofs) v += t;
            }
            if (tid < nb) btot[tid] = v - v0;
        }
    } else if (tid == 0) {
        int run = 0;
        for (int i = 0; i < nb; ++i) { const int v = btot[i]; btot[i] = run; run += v; }
    }
}

__global__ void addoff_kernel(int* __restrict__ off, int* __restrict__ cursor,
                              const int* __restrict__ btot, int n) {
    const int i = blockIdx.x * blockDim.x + threadIdx.x;
    if (i < n) {
        const int o = off[i] + btot[i >> 10];
        off[i] = o;
        cursor[i] = o;
    }
}

// ===========================================================================
// gemm1: y = x @ W1, output bf16 in QUARTER-MAJOR layout:
//   yq[((q*n)+node)*24 + j] = bf16( (x@W1)[node][q*24+j] )
// Each quarter slab is n*48 B = 2.4 MB -> fits one XCD's 4 MB L2.
// ===========================================================================
__global__ __launch_bounds__(256, 2)
void gemm1_kernel(const float* __restrict__ x,
                  const float* __restrict__ W,   // [96][96] [k][o]
                  ushort16* __restrict__ yq, int n) {
    __shared__ float Xs[NT][XPAD];     // 24.8 KB
    __shared__ float4 Ws[D * D4];      // 36.9 KB

    const int tid = threadIdx.x;
    for (int i = tid; i < D * D4; i += 256)
        Ws[i] = ((const float4*)W)[i];

    const int node_l = tid >> 2;
    const int qq = tid & 3;
    const int node = blockIdx.x * NT + node_l;

    if (node < n) {
        const float4* xr = ((const float4*)(x + (size_t)node * D)) + qq * 6;
#pragma unroll
        for (int j = 0; j < 6; ++j) {
            const float4 v = xr[j];
            Xs[node_l][qq * 24 + j * 4 + 0] = v.x;
            Xs[node_l][qq * 24 + j * 4 + 1] = v.y;
            Xs[node_l][qq * 24 + j * 4 + 2] = v.z;
            Xs[node_l][qq * 24 + j * 4 + 3] = v.w;
        }
    }
    __syncthreads();

    if (node < n) {
        float4 oacc[6];
#pragma unroll
        for (int j = 0; j < 6; ++j) oacc[j] = make_float4(0.f, 0.f, 0.f, 0.f);
#pragma unroll 4
        for (int k = 0; k < D; ++k) {
            const float xv = Xs[node_l][k];
            const float4* wrow = Ws + k * D4 + qq * 6;
#pragma unroll
            for (int j = 0; j < 6; ++j) {
                const float4 w = wrow[j];
                oacc[j].x += xv * w.x; oacc[j].y += xv * w.y;
                oacc[j].z += xv * w.z; oacc[j].w += xv * w.w;
            }
        }
        uint32 p[12];
#pragma unroll
        for (int j = 0; j < 6; ++j) {
            p[2 * j + 0] = pk_bf16(oacc[j].x, oacc[j].y);
            p[2 * j + 1] = pk_bf16(oacc[j].z, oacc[j].w);
        }
        uint4* dst = (uint4*)(yq + ((size_t)qq * n + node) * 24);
        dst[0] = make_uint4(p[0], p[1], p[2], p[3]);
        dst[1] = make_uint4(p[4], p[5], p[6], p[7]);
        dst[2] = make_uint4(p[8], p[9], p[10], p[11]);
    }
}

// ===========================================================================
// gather1z: per (node, quarter):
//   hq = relu( yq[node] + sum_src yq[src] + b1_q )     (24 values, registers)
//   (z0,z1) = hq . W2_q ; atomicAdd into z[node]
// Quarter bound to an XCD pair via blockIdx so each XCD's L2 sees one slab.
// ===========================================================================
__global__ __launch_bounds__(256)
void gather1z_kernel(const ushort16* __restrict__ yq,
                     const float* __restrict__ b1,   // [96]
                     const float* __restrict__ W2,   // [96][2]
                     const int* __restrict__ off,
                     const int* __restrict__ cnt,
                     const int* __restrict__ srcs,
                     float* __restrict__ z,          // [n][2], pre-zeroed
                     int n, int bpq) {
    const int blk = blockIdx.x;
    const int q = (blk & 7) >> 1;
    const int i = ((blk >> 3) << 1) | (blk & 1);
    if (i >= bpq) return;
    const int node = i * 256 + threadIdx.x;
    if (node >= n) return;

    const uint4* Y = (const uint4*)(yq + (size_t)q * n * 24);

    float acc[24];
    {
        const uint4* r = Y + (size_t)node * 3;
        const uint4 u0 = r[0], u1 = r[1], u2 = r[2];
        UNPK_SET(u0, 0) UNPK_SET(u1, 8) UNPK_SET(u2, 16)
    }

    const int s0 = off[node];
    const int deg = cnt[node];
    int p = 0;
    for (; p + 2 <= deg; p += 2) {
        const int sA = srcs[s0 + p];
        const int sB = srcs[s0 + p + 1];
        const uint4* rA = Y + (size_t)sA * 3;
        const uint4* rB = Y + (size_t)sB * 3;
        const uint4 a0 = rA[0], a1 = rA[1], a2 = rA[2];
        const uint4 c0 = rB[0], c1 = rB[1], c2 = rB[2];
        UNPK_ADD(a0, 0) UNPK_ADD(a1, 8) UNPK_ADD(a2, 16)
        UNPK_ADD(c0, 0) UNPK_ADD(c1, 8) UNPK_ADD(c2, 16)
    }
    if (p < deg) {
        const uint4* rA = Y + (size_t)srcs[s0 + p] * 3;
        const uint4 a0 = rA[0], a1 = rA[1], a2 = rA[2];
        UNPK_ADD(a0, 0) UNPK_ADD(a1, 8) UNPK_ADD(a2, 16)
    }

    const float* bq = b1 + q * 24;
    const float* wq = W2 + q * 48;
    float z0 = 0.f, z1 = 0.f;
#pragma unroll
    for (int j = 0; j < 24; ++j) {
        const float hv = fmaxf(acc[j] + bq[j], 0.0f);
        z0 += hv * wq[2 * j + 0];
        z1 += hv * wq[2 * j + 1];
    }
    atomicAdd(&z[2 * node + 0], z0);
    atomicAdd(&z[2 * node + 1], z1);
}

// ===========================================================================
// gather2: out = z[node] + sum_src z[src] + b2.  z is 400 KB, L2-hot.
// ===========================================================================
__global__ __launch_bounds__(256)
void gather2_kernel(const float* __restrict__ z,
                    const float* __restrict__ b,   // [2]
                    const int* __restrict__ off,
                    const int* __restrict__ cnt,
                    const int* __restrict__ srcs,
                    float* __restrict__ out, int n) {
    const int node = blockIdx.x * blockDim.x + threadIdx.x;
    if (node >= n) return;

    const float2 zi = ((const float2*)z)[node];
    float a0 = zi.x + b[0];
    float a1 = zi.y + b[1];

    const int s0 = off[node];
    const int deg = cnt[node];
    int p = 0;
    for (; p + 2 <= deg; p += 2) {
        const float2 vA = ((const float2*)z)[srcs[s0 + p]];
        const float2 vB = ((const float2*)z)[srcs[s0 + p + 1]];
        a0 += vA.x + vB.x;
        a1 += vA.y + vB.y;
    }
    if (p < deg) {
        const float2 vA = ((const float2*)z)[srcs[s0 + p]];
        a0 += vA.x;
        a1 += vA.y;
    }
    ((float2*)out)[node] = make_float2(a0, a1);
}

// ===========================================================================
extern "C" void kernel_launch(void* const* d_in, const int* in_sizes, int n_in,
                              void* d_out, int out_size, void* d_ws, size_t ws_size,
                              hipStream_t stream) {
    const float* x   = (const float*)d_in[0];
    const int*   eix = (const int*)d_in[1];
    const float* W1  = (const float*)d_in[2];
    const float* b1  = (const float*)d_in[3];
    const float* W2  = (const float*)d_in[4];
    const float* b2  = (const float*)d_in[5];
    float*       out = (float*)d_out;

    const int n = in_sizes[0] / D;       // 50000
    const int E = in_sizes[1] / 2;       // 800000
    const int* src = eix;
    const int* dst = eix + E;

    const int nb = (n + 1023) / 1024;

    // ws layout: yq (bf16, n*96) | z (f32, n*2) | cnt | off | cursor | btot | srcs
    ushort16* yq = (ushort16*)d_ws;
    float* z     = (float*)(yq + (size_t)n * D);
    int* cnt     = (int*)(z + 2 * (size_t)n);
    int* off     = cnt + n;
    int* cursor  = off + n;
    int* btot    = cursor + n;
    int* srcs    = btot + 1024;

    const int nper = (n + NXCD - 1) / NXCD;   // dst range per XCD
    const int nGroups = 384;                   // 384*8 = 3072 blocks

    // ---- init + CSR build (XCD-partitioned scatter phases) ----
    init_kernel<<<(n + 255) / 256, 256, 0, stream>>>(cnt, (float2*)z, n);
    hist_x_kernel<<<nGroups * NXCD, 256, 0, stream>>>(dst, cnt, E, nper, nGroups);
    blockscan_kernel<<<nb, 1024, 0, stream>>>(cnt, off, btot, n);
    scantot_kernel<<<1, 64, 0, stream>>>(btot, nb);
    addoff_kernel<<<(n + 255) / 256, 256, 0, stream>>>(off, cursor, btot, n);
    fill_x_kernel<<<nGroups * NXCD, 256, 0, stream>>>(src, dst, cursor, srcs, E, nper, nGroups);

    // ---- layer 1 GEMM: y = x@W1 (bf16, quarter-major) ----
    const int tiles = (n + NT - 1) / NT;
    gemm1_kernel<<<tiles, 256, 0, stream>>>(x, W1, yq, n);

    // ---- fused gather + bias/relu + W2 projection -> z ----
    const int bpq = (n + 255) / 256;
    const int g1grid = 8 * ((bpq + 1) / 2);
    gather1z_kernel<<<g1grid, 256, 0, stream>>>(yq, b1, W2, off, cnt, srcs, z, n, bpq);

    // ---- layer 2 gather: out = z_i + sum z_src + b2 ----
    gather2_kernel<<<(n + 255) / 256, 256, 0, stream>>>(z, b2, off, cnt, srcs, out, n);
}